// Round 2
// baseline (425.470 us; speedup 1.0000x reference)
//
#include <hip/hip_runtime.h>
#include <cstdint>

// LeNet-5 forward, B=16384. Batch-lane design: lane = sample, wave-uniform
// control, f32-accum dot2 math, f16 pair-packed storage.
// R8: all intermediate buffers are per-sample AoS ([N][feature]) so every
// load/store is per-lane-base + immediate offset (zero address VALU, dwordx2/4
// accesses). c3s4 plane loop specialized via switch(nic) -> template<NIC>
// fully unrolled (cross-plane load pipelining). Buffer SIZES and plan offsets
// are byte-identical to R7:
//   Plan A (ws >= 55,312,384): S2PA u32[16384][588] @0 (38,535,168);
//     XPA u32[8192][512] @38,535,168 (16,777,216, front); S4PA u32[16384][240]
//     @38,535,168 (15,728,640, after front); H5PA @0 (3,932,160);
//     H6PA @4,194,304 (2,752,512). 10 dispatches.
//   Plan B: XPA @0 (16,777,216); S2PA @16,777,216 (19,267,584);
//     S4PA @0 (7,864,320); H5PA @7,864,320 (1,966,080); H6PA @9,830,400
//     (1,376,256). peak 36,044,800. 13 dispatches.
// Weight pack lives at d_out tail (k_rbf never reads it; k_rbf rewrites all
// of out at the end).

typedef unsigned int u32;

union U32H2 { u32 u; _Float16 h[2]; };
__device__ __forceinline__ float f16lo(u32 v) { U32H2 a; a.u = v; return (float)a.h[0]; }
__device__ __forceinline__ float f16hi(u32 v) { U32H2 a; a.u = v; return (float)a.h[1]; }
__device__ __forceinline__ u32 packh2(float a, float b) {
    U32H2 x; x.h[0] = (_Float16)a; x.h[1] = (_Float16)b; return x.u;
}

typedef _Float16 h2v __attribute__((ext_vector_type(2)));
union U32V2 { u32 u; h2v v; };

#if defined(__has_builtin)
#if __has_builtin(__builtin_amdgcn_fdot2)
#define HAVE_FDOT2 1
#endif
#endif

// c += a.h0*b.h0 + a.h1*b.h1  (f16 mul, f32 accumulate) -> v_dot2_f32_f16
__device__ __forceinline__ float dot2(u32 a, u32 b, float c) {
    U32V2 x, y; x.u = a; y.u = b;
#ifdef HAVE_FDOT2
    return __builtin_amdgcn_fdot2(x.v, y.v, c, false);
#else
    return c + (float)x.v[0] * (float)y.v[0] + (float)x.v[1] * (float)y.v[1];
#endif
}

// pair starting at odd position: (hi(lo_pair), lo(hi_pair)) -> v_alignbit_b32
__device__ __forceinline__ u32 shf16(u32 lo, u32 hi) {
    return (lo >> 16) | (hi << 16);
}

// A*tanh(S*v), S=2/3: tanh(y) = 1 - 2/(exp(2y)+1), 2y = (4/3)v
__device__ __forceinline__ float tact(float v) {
    float e = __expf(1.3333333333f * v);
    return 1.7159f * (1.0f - 2.0f * __builtin_amdgcn_rcpf(e + 1.0f));
}

// C3 sparse connection lists (from reference CONNECTIONS)
__device__ const int C3_NIC[16] = {3,3,3,3,3,3, 4,4,4,4,4,4,4,4,4, 6};
__device__ const int C3_ICL[96] = {
    0,1,2,0,0,0,  1,2,3,0,0,0,  2,3,4,0,0,0,  3,4,5,0,0,0,
    0,4,5,0,0,0,  0,1,5,0,0,0,  0,1,2,3,0,0,  1,2,3,4,0,0,
    2,3,4,5,0,0,  0,3,4,5,0,0,  0,1,4,5,0,0,  0,1,2,5,0,0,
    0,1,3,4,0,0,  1,2,4,5,0,0,  0,2,3,5,0,0,  0,1,2,3,4,5 };

// Weight-pack layout (u32 indices inside WPK):
//  W1P @0     : [6ch][5ky][3q]   pair = (w[2q], w[2q+1]|0)         (90, pad 96)
//  W3P @96    : [96 plane][5][3] same                              (1440)
//  W5P @1536  : [120c][80g][3q]  pair = (w5[c][g*5+2q], +1|0)      (28800)
//  F6P @30336 : [84o][60i]       pair = (f6w[o][2i], f6w[o][2i+1]) (5040)
#define WPK_W1 0
#define WPK_W3 96
#define WPK_W5 1536
#define WPK_F6 30336
#define WPK_N  35376

__global__ __launch_bounds__(256) void k_wpack(
    const float* __restrict__ w1, const float* __restrict__ w3,
    const float* __restrict__ w5, const float* __restrict__ f6w,
    u32* __restrict__ wpk)
{
    const int idx = blockIdx.x * 256 + threadIdx.x;
    if (idx >= WPK_N) return;
    float a = 0.0f, b = 0.0f;
    if (idx < 96) {
        if (idx < 90) {
            int ch = idx / 15, r = idx % 15, ky = r / 3, q = r % 3;
            a = w1[ch * 25 + ky * 5 + 2 * q];
            if (q < 2) b = w1[ch * 25 + ky * 5 + 2 * q + 1];
        }
    } else if (idx < WPK_W5) {
        int t = idx - WPK_W3;
        int p = t / 15, r = t % 15, ky = r / 3, q = r % 3;
        a = w3[p * 25 + ky * 5 + 2 * q];
        if (q < 2) b = w3[p * 25 + ky * 5 + 2 * q + 1];
    } else if (idx < WPK_F6) {
        int t = idx - WPK_W5;
        int c = t / 240, r = t % 240, g = r / 3, q = r % 3;
        a = w5[c * 400 + g * 5 + 2 * q];
        if (q < 2) b = w5[c * 400 + g * 5 + 2 * q + 1];
    } else {
        int t = idx - WPK_F6;
        int o = t / 60, i = t % 60;
        a = f6w[o * 120 + 2 * i];
        b = f6w[o * 120 + 2 * i + 1];
    }
    wpk[idx] = packh2(a, b);
}

// ---------------- transpose-to-f16: x chunk (8192,1024) f32 -> AoS ----------
// xpa[sl][r*16+j] = (x[sl][r*32+2j], x[sl][r*32+2j+1]) f16 pair.
// Per-lane contiguous 512B read / 256B write (>= line size, no LDS needed).
// grid (32, 8).
__global__ __launch_bounds__(256) void k_tr(const float* __restrict__ x,
                                            u32* __restrict__ xpa)
{
    const int sl = blockIdx.x * 256 + threadIdx.x;
    const int seg = blockIdx.y;              // 0..7: 128 floats / 64 pairs each
    const float4* xb = (const float4*)(x + (size_t)sl * 1024 + seg * 128);
    uint4* ob = (uint4*)(xpa + (size_t)sl * 512 + seg * 64);
    #pragma unroll
    for (int k = 0; k < 16; ++k) {
        float4 a = xb[2 * k];
        float4 b = xb[2 * k + 1];
        uint4 o;
        o.x = packh2(a.x, a.y); o.y = packh2(a.z, a.w);
        o.z = packh2(b.x, b.y); o.w = packh2(b.z, b.w);
        ob[k] = o;
    }
}

// ---------------- C1 + S2 fused, grid (32, 42) ------------------------------
// blockIdx.y = oy2*3 + chpair. S2PA AoS: s2pa[sl][ch*98 + row*7 + p] holds
// s2 row `row` cols (2p, 2p+1) as an f16 pair (row cols 0..6 from conv row
// 2row, 7..13 from conv row 2row+1, per pool_affine reshape semantics).
__global__ __launch_bounds__(256) void k_c1s2(
    const u32* __restrict__ xpa, const u32* __restrict__ wpk,
    const float* __restrict__ b1,
    const float* __restrict__ s2w, const float* __restrict__ s2b,
    u32* __restrict__ s2pa)
{
    const int sl = blockIdx.x * 256 + threadIdx.x;
    const int oy2 = blockIdx.y / 3;
    const int cp  = blockIdx.y % 3;          // channels 2cp, 2cp+1
    const int y0 = 2 * oy2;
    const u32* xb = xpa + (size_t)sl * 512 + y0 * 16;  // immediate offsets below

    u32 wl[2][15];                           // f16 weight pairs (uniform)
    #pragma unroll
    for (int a = 0; a < 2; ++a)
        #pragma unroll
        for (int i = 0; i < 15; ++i) wl[a][i] = wpk[WPK_W1 + (2 * cp + a) * 15 + i];

    u32 cur[6][4];                           // aligned pairs, window cols 4qx..4qx+7
    #pragma unroll
    for (int r = 0; r < 6; ++r)
        #pragma unroll
        for (int c = 0; c < 4; ++c)
            cur[r][c] = xb[r * 16 + c];

    float va[2][7], vb[2][7];                // s2 row cols 0..6 / 7..13 per ch

    #pragma unroll
    for (int qx = 0; qx < 7; ++qx) {
        float o[2][2][4];
        #pragma unroll
        for (int a = 0; a < 2; ++a) {
            const float bbv = b1[2 * cp + a];
            #pragma unroll
            for (int u = 0; u < 2; ++u)
                #pragma unroll
                for (int d = 0; d < 4; ++d) o[a][u][d] = bbv;
        }
        #pragma unroll
        for (int r = 0; r < 6; ++r) {
            const u32 s0 = shf16(cur[r][0], cur[r][1]);
            const u32 s1 = shf16(cur[r][1], cur[r][2]);
            const u32 s2 = shf16(cur[r][2], cur[r][3]);
            const u32 s3 = cur[r][3] >> 16;  // (col7, pad0)
            #pragma unroll
            for (int u = 0; u < 2; ++u) {
                const int ky = r - u;
                if (ky < 0 || ky > 4) continue;
                #pragma unroll
                for (int a = 0; a < 2; ++a) {
                    const u32 w0 = wl[a][ky * 3 + 0];
                    const u32 w1 = wl[a][ky * 3 + 1];
                    const u32 w2 = wl[a][ky * 3 + 2];
                    o[a][u][0] = dot2(cur[r][0], w0, dot2(cur[r][1], w1, dot2(cur[r][2], w2, o[a][u][0])));
                    o[a][u][1] = dot2(s0,        w0, dot2(s1,        w1, dot2(s2,        w2, o[a][u][1])));
                    o[a][u][2] = dot2(cur[r][1], w0, dot2(cur[r][2], w1, dot2(cur[r][3], w2, o[a][u][2])));
                    o[a][u][3] = dot2(s1,        w0, dot2(s2,        w1, dot2(s3,        w2, o[a][u][3])));
                }
            }
        }
        #pragma unroll
        for (int a = 0; a < 2; ++a) {
            const int ch = 2 * cp + a;
            const float sw = s2w[ch], sb = s2b[ch];
            float m0 = 0.25f * (tact(o[a][0][0]) + tact(o[a][0][1]) + tact(o[a][0][2]) + tact(o[a][0][3]));
            float m1 = 0.25f * (tact(o[a][1][0]) + tact(o[a][1][1]) + tact(o[a][1][2]) + tact(o[a][1][3]));
            va[a][qx] = tact(sw * m0 + sb);
            vb[a][qx] = tact(sw * m1 + sb);
        }
        if (qx < 6) {                        // slide window: +2 new pairs/row
            #pragma unroll
            for (int r = 0; r < 6; ++r) {
                cur[r][0] = cur[r][2];
                cur[r][1] = cur[r][3];
                cur[r][2] = xb[r * 16 + 2 * qx + 4];
                cur[r][3] = xb[r * 16 + 2 * qx + 5];
            }
        }
    }
    // adjacent-column pairs of the 14-value s2 row -> 7 contiguous u32/ch
    #pragma unroll
    for (int a = 0; a < 2; ++a) {
        u32 o7[7];
        o7[0] = packh2(va[a][0], va[a][1]);
        o7[1] = packh2(va[a][2], va[a][3]);
        o7[2] = packh2(va[a][4], va[a][5]);
        o7[3] = packh2(va[a][6], vb[a][0]);
        o7[4] = packh2(vb[a][1], vb[a][2]);
        o7[5] = packh2(vb[a][3], vb[a][4]);
        o7[6] = packh2(vb[a][5], vb[a][6]);
        const int ch = 2 * cp + a;
        u32* op = s2pa + (size_t)sl * 588 + ch * 98 + oy2 * 7;
        // byte alignment of op: 8B iff oy2 even (sl*2352 and ch*98*4 are 8B mult)
        if ((oy2 & 1) == 0) {
            uint2 t;
            t.x = o7[0]; t.y = o7[1]; *(uint2*)(op + 0) = t;
            t.x = o7[2]; t.y = o7[3]; *(uint2*)(op + 2) = t;
            t.x = o7[4]; t.y = o7[5]; *(uint2*)(op + 4) = t;
            op[6] = o7[6];
        } else {
            op[0] = o7[0];
            uint2 t;
            t.x = o7[1]; t.y = o7[2]; *(uint2*)(op + 1) = t;
            t.x = o7[3]; t.y = o7[4]; *(uint2*)(op + 3) = t;
            t.x = o7[5]; t.y = o7[6]; *(uint2*)(op + 5) = t;
        }
    }
}

// ---------------- C3 + S4 fused, grid (nb/256, 80) --------------------------
// blockIdx.y = oc*5 + y2. Window per plane = 42 CONSECUTIVE u32 (21 aligned
// uint2 loads, immediate offsets) = rows 2y2..2y2+5 x 7 adjacent-col pairs.
template<int NIC>
__device__ __forceinline__ void c3_body(
    const u32* __restrict__ pb, const u32* __restrict__ wpk,
    const int* __restrict__ icl, int oc, int y2, float a2[2][10])
{
    #pragma unroll
    for (int e = 0; e < NIC; ++e) {          // fully unrolled plane loop
        const int ic = icl[e];
        const uint2* sp = (const uint2*)(pb + ic * 98 + 14 * y2);  // even -> 8B
        u32 wf[42];
        #pragma unroll
        for (int k = 0; k < 21; ++k) {
            const uint2 v = sp[k];
            wf[2 * k] = v.x; wf[2 * k + 1] = v.y;
        }
        u32 wl[15];                          // uniform f16 weight pairs
        #pragma unroll
        for (int i = 0; i < 15; ++i) wl[i] = wpk[WPK_W3 + (oc * 6 + ic) * 15 + i];
        #pragma unroll
        for (int r = 0; r < 6; ++r) {
            const u32* wa = wf + 7 * r;
            u32 sh[7];                       // odd-start pairs for this row
            #pragma unroll
            for (int j = 0; j < 6; ++j) sh[j] = shf16(wa[j], wa[j + 1]);
            sh[6] = wa[6] >> 16;             // (col13, pad0)
            #pragma unroll
            for (int u = 0; u < 2; ++u) {
                const int ky = r - u;
                if (ky < 0 || ky > 4) continue;
                const u32 w0 = wl[ky * 3 + 0];
                const u32 w1 = wl[ky * 3 + 1];
                const u32 w2 = wl[ky * 3 + 2];
                #pragma unroll
                for (int p = 0; p < 5; ++p) {
                    a2[u][2 * p]     = dot2(wa[p], w0, dot2(wa[p + 1], w1, dot2(wa[p + 2], w2, a2[u][2 * p])));
                    a2[u][2 * p + 1] = dot2(sh[p], w0, dot2(sh[p + 1], w1, dot2(sh[p + 2], w2, a2[u][2 * p + 1])));
                }
            }
        }
    }
}

__global__ __launch_bounds__(256) void k_c3s4(
    const u32* __restrict__ s2pa, const u32* __restrict__ wpk,
    const float* __restrict__ b3, const float* __restrict__ s4w,
    const float* __restrict__ s4b, u32* __restrict__ s4pa)
{
    const int sl = blockIdx.x * 256 + threadIdx.x;
    const int oc = blockIdx.y / 5;
    const int y2 = blockIdx.y % 5;
    const u32* pb = s2pa + (size_t)sl * 588;
    const int* icl = &C3_ICL[oc * 6];
    const float bbv = b3[oc];

    float a2[2][10];
    #pragma unroll
    for (int u = 0; u < 2; ++u)
        #pragma unroll
        for (int ox = 0; ox < 10; ++ox) a2[u][ox] = bbv;

    switch (C3_NIC[oc]) {                    // uniform scalar branch
        case 3:  c3_body<3>(pb, wpk, icl, oc, y2, a2); break;
        case 4:  c3_body<4>(pb, wpk, icl, oc, y2, a2); break;
        default: c3_body<6>(pb, wpk, icl, oc, y2, a2); break;
    }

    // tanh, then S4 reshape-flat pooling over local flat f = u*10+ox
    float tv[20];
    #pragma unroll
    for (int u = 0; u < 2; ++u)
        #pragma unroll
        for (int ox = 0; ox < 10; ++ox) tv[u * 10 + ox] = tact(a2[u][ox]);
    const float swv = s4w[oc], sbv = s4b[oc];
    float so[5];
    #pragma unroll
    for (int x2 = 0; x2 < 5; ++x2)
        so[x2] = tact(0.25f * (tv[x2 * 4] + tv[x2 * 4 + 1] + tv[x2 * 4 + 2] + tv[x2 * 4 + 3]) * swv + sbv);
    u32* op = s4pa + (size_t)sl * 240 + (oc * 5 + y2) * 3;
    op[0] = packh2(so[0], so[1]);
    op[1] = packh2(so[2], so[3]);
    op[2] = packh2(so[4], 0.0f);
}

// ---------------- C5: 120-ch GEMV over 240 s4 pairs, grid (nb/256, 12) ------
__global__ __launch_bounds__(256) void k_c5(
    const u32* __restrict__ s4pa, const u32* __restrict__ wpk,
    const float* __restrict__ b5, u32* __restrict__ h5pa)
{
    const int sl = blockIdx.x * 256 + threadIdx.x;
    const int chg = blockIdx.y;              // channels chg*10 .. chg*10+9
    const uint4* sb = (const uint4*)(s4pa + (size_t)sl * 240);  // 16B aligned
    const u32* wb = wpk + WPK_W5 + chg * 2400;
    float acc[10];
    #pragma unroll
    for (int c = 0; c < 10; ++c) acc[c] = b5[chg * 10 + c];
    #pragma unroll 4
    for (int k = 0; k < 60; ++k) {
        const uint4 v = sb[k];
        #pragma unroll
        for (int c = 0; c < 10; ++c) {
            const u32* wp = wb + c * 240 + 4 * k;   // uniform -> s_load
            acc[c] = dot2(v.w, wp[3], dot2(v.z, wp[2],
                     dot2(v.y, wp[1], dot2(v.x, wp[0], acc[c]))));
        }
    }
    u32* op = h5pa + (size_t)sl * 60 + chg * 5;
    #pragma unroll
    for (int j = 0; j < 5; ++j)
        op[j] = packh2(tact(acc[2 * j]), tact(acc[2 * j + 1]));
}

// ---------------- F6: 84-out GEMV over 60 h5 pairs, grid (nb/256, 6) --------
__global__ __launch_bounds__(256) void k_f6(
    const u32* __restrict__ h5pa, const u32* __restrict__ wpk,
    const float* __restrict__ f6b, u32* __restrict__ h6pa)
{
    const int sl = blockIdx.x * 256 + threadIdx.x;
    const int og = blockIdx.y;               // outputs og*14 .. og*14+13
    const uint4* hb = (const uint4*)(h5pa + (size_t)sl * 60);   // 16B aligned
    const u32* wb = wpk + WPK_F6 + og * 14 * 60;
    float acc[14];
    #pragma unroll
    for (int o = 0; o < 14; ++o) acc[o] = f6b[og * 14 + o];
    #pragma unroll
    for (int k = 0; k < 15; ++k) {
        const uint4 v = hb[k];
        #pragma unroll
        for (int o = 0; o < 14; ++o) {
            const u32* wp = wb + o * 60 + 4 * k;    // uniform -> s_load
            acc[o] = dot2(v.w, wp[3], dot2(v.z, wp[2],
                     dot2(v.y, wp[1], dot2(v.x, wp[0], acc[o]))));
        }
    }
    u32* op = h6pa + (size_t)sl * 42 + og * 7;
    #pragma unroll
    for (int j = 0; j < 7; ++j)
        op[j] = packh2(tact(acc[2 * j]), tact(acc[2 * j + 1]));
}

// ---------------- RBF head, grid (nb/256, 5): 2 classes per block -----------
__global__ __launch_bounds__(256) void k_rbf(
    const u32* __restrict__ h6pa, const float* __restrict__ rbf,
    float* __restrict__ out)
{
    const int sl = blockIdx.x * 256 + threadIdx.x;
    const int gy = blockIdx.y;
    const uint2* hb = (const uint2*)(h6pa + (size_t)sl * 42);   // 8B aligned
    float hv[84];
    #pragma unroll
    for (int i = 0; i < 21; ++i) {
        const uint2 v = hb[i];
        hv[4 * i]     = f16lo(v.x);
        hv[4 * i + 1] = f16hi(v.x);
        hv[4 * i + 2] = f16lo(v.y);
        hv[4 * i + 3] = f16hi(v.y);
    }
    #pragma unroll
    for (int a = 0; a < 2; ++a) {
        const int c = 2 * gy + a;
        float acc = 0.0f;
        #pragma unroll 4
        for (int i = 0; i < 84; ++i) {
            float d = hv[i] - rbf[c * 84 + i];   // uniform -> s_load
            acc += d * d;
        }
        out[(size_t)sl * 10 + c] = acc;
    }
}

extern "C" void kernel_launch(void* const* d_in, const int* in_sizes, int n_in,
                              void* d_out, int out_size, void* d_ws, size_t ws_size,
                              hipStream_t stream)
{
    const float* x    = (const float*)d_in[0];
    const float* w1   = (const float*)d_in[1];
    const float* b1   = (const float*)d_in[2];
    const float* s2w  = (const float*)d_in[3];
    const float* s2b  = (const float*)d_in[4];
    const float* w3   = (const float*)d_in[5];
    const float* b3   = (const float*)d_in[6];
    const float* s4w  = (const float*)d_in[7];
    const float* s4b  = (const float*)d_in[8];
    const float* w5   = (const float*)d_in[9];
    const float* b5   = (const float*)d_in[10];
    const float* f6w  = (const float*)d_in[11];
    const float* f6b  = (const float*)d_in[12];
    const float* rbfw = (const float*)d_in[13];
    float* out = (float*)d_out;
    char* ws = (char*)d_ws;

    // Weight pack at the tail of d_out (dead until k_rbf; k_rbf never reads
    // it and rewrites every byte of out at the end of each plan/chunk order).
    u32* WPK = (u32*)((char*)d_out +
                      (((size_t)out_size - (size_t)(WPK_N * 4)) & ~(size_t)7));
    k_wpack<<<dim3((WPK_N + 255) / 256), 256, 0, stream>>>(w1, w3, w5, f6w, WPK);

    if (ws_size >= 55312384) {
        // ---- Plan A: full-batch tail (10 dispatches) ----
        u32* S2P = (u32*)(ws);                       // 38,535,168 B
        u32* XP  = (u32*)(ws + 38535168);            // 16,777,216 B (front)
        u32* S4P = (u32*)(ws + 38535168);            // 15,728,640 B (after front)
        u32* H5P = (u32*)(ws);                       //  3,932,160 B (after c3s4)
        u32* H6P = (u32*)(ws + 4194304);             //  2,752,512 B
        for (int c = 0; c < 2; ++c) {
            k_tr  <<<dim3(32, 8), 256, 0, stream>>>(x + (size_t)c * 8192 * 1024, XP);
            k_c1s2<<<dim3(32, 42), 256, 0, stream>>>(XP, WPK, b1, s2w, s2b,
                                                     S2P + (size_t)c * 8192 * 588);
        }
        k_c3s4<<<dim3(64, 80), 256, 0, stream>>>(S2P, WPK, b3, s4w, s4b, S4P);
        k_c5  <<<dim3(64, 12), 256, 0, stream>>>(S4P, WPK, b5, H5P);
        k_f6  <<<dim3(64, 6), 256, 0, stream>>>(H5P, WPK, f6b, H6P);
        k_rbf <<<dim3(64, 5), 256, 0, stream>>>(H6P, rbfw, out);
    } else {
        // ---- Plan B: 2 chunks (13 dispatches) ----
        u32* XP  = (u32*)(ws);                       // 16,777,216 B
        u32* S2P = (u32*)(ws + 16777216);            // 19,267,584 B
        u32* S4P = (u32*)(ws);                       //  7,864,320 B (XP dead)
        u32* H5P = (u32*)(ws + 7864320);             //  1,966,080 B
        u32* H6P = (u32*)(ws + 9830400);             //  1,376,256 B
        for (int c = 0; c < 2; ++c) {
            k_tr  <<<dim3(32, 8), 256, 0, stream>>>(x + (size_t)c * 8192 * 1024, XP);
            k_c1s2<<<dim3(32, 42), 256, 0, stream>>>(XP, WPK, b1, s2w, s2b, S2P);
            k_c3s4<<<dim3(32, 80), 256, 0, stream>>>(S2P, WPK, b3, s4w, s4b, S4P);
            k_c5  <<<dim3(32, 12), 256, 0, stream>>>(S4P, WPK, b5, H5P);
            k_f6  <<<dim3(32, 6), 256, 0, stream>>>(H5P, WPK, f6b, H6P);
            k_rbf <<<dim3(32, 5), 256, 0, stream>>>(H6P, rbfw, out + (size_t)c * 8192 * 10);
        }
    }
}

// Round 3
// 321.536 us; speedup vs baseline: 1.3232x; 1.3232x over previous
//
#include <hip/hip_runtime.h>
#include <cstdint>

// LeNet-5 forward, B=16384. Batch-lane design: lane = sample, wave-uniform
// control, [feature][N] SoA layouts (coalesced: lane index = sample column),
// f32-accum dot2 math, f16 pair-packed storage.
// R9 = R7 (proven 333us) + two VALU cuts, no layout changes:
//  (a) shifted-weight pairs (0,w0)(w1,w2)(w3,w4) precomputed in k_wpack ->
//      odd conv columns dot aligned activation pairs; all shf16/alignbit
//      removed from c1s2 (168/thread) and c3s4 (42/plane-window).
//  (b) c3s4 plane loop specialized switch(nic) -> template<NIC> full unroll
//      (cross-plane load pipelining).
// Plans/offsets identical to R7:
//   Plan A (ws >= 55,312,384): S2P uint2[294][16384] @0 (38,535,168);
//     XP @38,535,168 (16,777,216, front); S4P u32[240][16384] @38,535,168
//     (15,728,640, after front); H5P @0 (3,932,160); H6P @4,194,304
//     (2,752,512). 10 dispatches.
//   Plan B: XP @0 (16,777,216); S2P @16,777,216 (19,267,584); S4P @0
//     (7,864,320); H5P @7,864,320 (1,966,080); H6P @9,830,400 (1,376,256).
//     peak 36,044,800. 13 dispatches.
// Weight pack lives at d_out tail (k_rbf never reads it; k_rbf rewrites all
// of out after the pack's last consumer).

typedef unsigned int u32;

union U32H2 { u32 u; _Float16 h[2]; };
__device__ __forceinline__ float f16lo(u32 v) { U32H2 a; a.u = v; return (float)a.h[0]; }
__device__ __forceinline__ float f16hi(u32 v) { U32H2 a; a.u = v; return (float)a.h[1]; }
__device__ __forceinline__ u32 packh2(float a, float b) {
    U32H2 x; x.h[0] = (_Float16)a; x.h[1] = (_Float16)b; return x.u;
}

typedef _Float16 h2v __attribute__((ext_vector_type(2)));
union U32V2 { u32 u; h2v v; };

#if defined(__has_builtin)
#if __has_builtin(__builtin_amdgcn_fdot2)
#define HAVE_FDOT2 1
#endif
#endif

// c += a.h0*b.h0 + a.h1*b.h1  (f16 mul, f32 accumulate) -> v_dot2_f32_f16
__device__ __forceinline__ float dot2(u32 a, u32 b, float c) {
    U32V2 x, y; x.u = a; y.u = b;
#ifdef HAVE_FDOT2
    return __builtin_amdgcn_fdot2(x.v, y.v, c, false);
#else
    return c + (float)x.v[0] * (float)y.v[0] + (float)x.v[1] * (float)y.v[1];
#endif
}

// A*tanh(S*v), S=2/3: tanh(y) = 1 - 2/(exp(2y)+1), 2y = (4/3)v
__device__ __forceinline__ float tact(float v) {
    float e = __expf(1.3333333333f * v);
    return 1.7159f * (1.0f - 2.0f * __builtin_amdgcn_rcpf(e + 1.0f));
}

// C3 sparse connection lists (from reference CONNECTIONS)
__device__ const int C3_NIC[16] = {3,3,3,3,3,3, 4,4,4,4,4,4,4,4,4, 6};
__device__ const int C3_ICL[96] = {
    0,1,2,0,0,0,  1,2,3,0,0,0,  2,3,4,0,0,0,  3,4,5,0,0,0,
    0,4,5,0,0,0,  0,1,5,0,0,0,  0,1,2,3,0,0,  1,2,3,4,0,0,
    2,3,4,5,0,0,  0,3,4,5,0,0,  0,1,4,5,0,0,  0,1,2,5,0,0,
    0,1,3,4,0,0,  1,2,4,5,0,0,  0,2,3,5,0,0,  0,1,2,3,4,5 };

// Weight-pack layout (u32 indices inside WPK):
//  W1P  @0     : [6ch][5ky][3q]   pair = (w[2q], w[2q+1]|0)          (90, pad 96)
//  W1S  @96    : [6ch][5ky][3q]   pair = (0,w0)|(w1,w2)|(w3,w4)      (90, pad 96)
//  W3P  @192   : [96 plane][5][3] aligned                            (1440)
//  W3S  @1632  : [96 plane][5][3] shifted                            (1440)
//  W5P  @3072  : [120c][80g][3q]  pair = (w5[c][g*5+2q], +1|0)       (28800)
//  F6P  @31872 : [84o][60i]       pair = (f6w[o][2i], f6w[o][2i+1])  (5040)
#define WPK_W1  0
#define WPK_W1S 96
#define WPK_W3  192
#define WPK_W3S 1632
#define WPK_W5  3072
#define WPK_F6  31872
#define WPK_N   36912

__global__ __launch_bounds__(256) void k_wpack(
    const float* __restrict__ w1, const float* __restrict__ w3,
    const float* __restrict__ w5, const float* __restrict__ f6w,
    u32* __restrict__ wpk)
{
    const int idx = blockIdx.x * 256 + threadIdx.x;
    if (idx >= WPK_N) return;
    float a = 0.0f, b = 0.0f;
    if (idx < 192) {                         // w1 aligned / shifted
        const int s = idx >= 96;
        const int t = idx - s * 96;
        if (t < 90) {
            int ch = t / 15, r = t % 15, ky = r / 3, q = r % 3;
            const float* w = w1 + ch * 25 + ky * 5;
            if (!s) { a = w[2 * q]; if (q < 2) b = w[2 * q + 1]; }
            else if (q == 0) { b = w[0]; }
            else { a = w[2 * q - 1]; b = w[2 * q]; }
        }
    } else if (idx < WPK_W5) {               // w3 aligned / shifted
        const int s = (idx - WPK_W3) >= 1440;
        const int t = idx - WPK_W3 - s * 1440;
        int p = t / 15, r = t % 15, ky = r / 3, q = r % 3;
        const float* w = w3 + p * 25 + ky * 5;
        if (!s) { a = w[2 * q]; if (q < 2) b = w[2 * q + 1]; }
        else if (q == 0) { b = w[0]; }
        else { a = w[2 * q - 1]; b = w[2 * q]; }
    } else if (idx < WPK_F6) {
        int t = idx - WPK_W5;
        int c = t / 240, r = t % 240, g = r / 3, q = r % 3;
        a = w5[c * 400 + g * 5 + 2 * q];
        if (q < 2) b = w5[c * 400 + g * 5 + 2 * q + 1];
    } else {
        int t = idx - WPK_F6;
        int o = t / 60, i = t % 60;
        a = f6w[o * 120 + 2 * i];
        b = f6w[o * 120 + 2 * i + 1];
    }
    wpk[idx] = packh2(a, b);
}

// ---------------- transpose: x chunk (8192,1024) f32 -> xp u32[512][8192] ---
// xp[r*16+j][sl] = (x[r][2j], x[r][2j+1]) f16 pair. grid (128, 16).
__global__ __launch_bounds__(256) void k_tr(const float* __restrict__ x,
                                            u32* __restrict__ xp)
{
    __shared__ _Float16 lds[64 * 66];
    const int t = threadIdx.x;
    const int tb = blockIdx.x * 64;          // sample tile
    const int tp = blockIdx.y * 64;          // position tile
    #pragma unroll
    for (int i = 0; i < 16; ++i) {           // coalesced read along positions
        int idx = i * 256 + t;
        int bl = idx >> 6, pl = idx & 63;
        lds[pl * 66 + bl] = (_Float16)x[(size_t)(tb + bl) * 1024 + tp + pl];
    }
    __syncthreads();
    #pragma unroll
    for (int j = 0; j < 8; ++j) {            // coalesced pair-write along batch
        int idx = j * 256 + t;
        int pp = idx >> 6, bl = idx & 63;    // pp in [0,32)
        U32H2 u;
        u.h[0] = lds[(2 * pp) * 66 + bl];
        u.h[1] = lds[(2 * pp + 1) * 66 + bl];
        xp[(size_t)(blockIdx.y * 32 + pp) * 8192 + tb + bl] = u.u;
    }
}

// ---------------- C1 + S2 fused, grid (32, 42) ------------------------------
// blockIdx.y = oy2*3 + chpair. S2P: adjacent-column pairs in [fh][N][2] u32
// cells: feature f = ch*98 + row*7 + p holds s2 row `row` cols (2p, 2p+1)
// (row cols 0..6 from conv row 2row, 7..13 from conv row 2row+1, per
// pool_affine reshape semantics). Odd conv columns via shifted weight pairs.
__global__ __launch_bounds__(256) void k_c1s2(
    const u32* __restrict__ xp, const u32* __restrict__ wpk,
    const float* __restrict__ b1,
    const float* __restrict__ s2w, const float* __restrict__ s2b,
    u32* __restrict__ s2p, int ostr)
{
    const int sl = blockIdx.x * 256 + threadIdx.x;
    const int oy2 = blockIdx.y / 3;
    const int cp  = blockIdx.y % 3;          // channels 2cp, 2cp+1
    const int y0 = 2 * oy2;
    const u32* xb = xp + sl;

    u32 wl[2][15], wls[2][15];               // aligned + shifted pairs (uniform)
    #pragma unroll
    for (int a = 0; a < 2; ++a) {
        #pragma unroll
        for (int i = 0; i < 15; ++i) wl[a][i]  = wpk[WPK_W1  + (2 * cp + a) * 15 + i];
        #pragma unroll
        for (int i = 0; i < 15; ++i) wls[a][i] = wpk[WPK_W1S + (2 * cp + a) * 15 + i];
    }

    u32 cur[6][4];                           // aligned pairs, window cols 4qx..4qx+7
    #pragma unroll
    for (int r = 0; r < 6; ++r)
        #pragma unroll
        for (int c = 0; c < 4; ++c)
            cur[r][c] = xb[(size_t)((y0 + r) * 16 + c) * 8192];

    float va[2][7], vb[2][7];                // s2 row cols 0..6 / 7..13 per ch

    #pragma unroll
    for (int qx = 0; qx < 7; ++qx) {
        float o[2][2][4];
        #pragma unroll
        for (int a = 0; a < 2; ++a) {
            const float bbv = b1[2 * cp + a];
            #pragma unroll
            for (int u = 0; u < 2; ++u)
                #pragma unroll
                for (int d = 0; d < 4; ++d) o[a][u][d] = bbv;
        }
        #pragma unroll
        for (int r = 0; r < 6; ++r) {
            #pragma unroll
            for (int u = 0; u < 2; ++u) {
                const int ky = r - u;
                if (ky < 0 || ky > 4) continue;
                #pragma unroll
                for (int a = 0; a < 2; ++a) {
                    const u32 w0 = wl[a][ky * 3 + 0];
                    const u32 w1 = wl[a][ky * 3 + 1];
                    const u32 w2 = wl[a][ky * 3 + 2];
                    const u32 v0 = wls[a][ky * 3 + 0];
                    const u32 v1 = wls[a][ky * 3 + 1];
                    const u32 v2 = wls[a][ky * 3 + 2];
                    o[a][u][0] = dot2(cur[r][0], w0, dot2(cur[r][1], w1, dot2(cur[r][2], w2, o[a][u][0])));
                    o[a][u][1] = dot2(cur[r][0], v0, dot2(cur[r][1], v1, dot2(cur[r][2], v2, o[a][u][1])));
                    o[a][u][2] = dot2(cur[r][1], w0, dot2(cur[r][2], w1, dot2(cur[r][3], w2, o[a][u][2])));
                    o[a][u][3] = dot2(cur[r][1], v0, dot2(cur[r][2], v1, dot2(cur[r][3], v2, o[a][u][3])));
                }
            }
        }
        #pragma unroll
        for (int a = 0; a < 2; ++a) {
            const int ch = 2 * cp + a;
            const float sw = s2w[ch], sb = s2b[ch];
            float m0 = 0.25f * (tact(o[a][0][0]) + tact(o[a][0][1]) + tact(o[a][0][2]) + tact(o[a][0][3]));
            float m1 = 0.25f * (tact(o[a][1][0]) + tact(o[a][1][1]) + tact(o[a][1][2]) + tact(o[a][1][3]));
            va[a][qx] = tact(sw * m0 + sb);
            vb[a][qx] = tact(sw * m1 + sb);
        }
        if (qx < 6) {                        // slide window: +2 new pairs/row
            #pragma unroll
            for (int r = 0; r < 6; ++r) {
                cur[r][0] = cur[r][2];
                cur[r][1] = cur[r][3];
                cur[r][2] = xb[(size_t)((y0 + r) * 16 + 2 * qx + 4) * 8192];
                cur[r][3] = xb[(size_t)((y0 + r) * 16 + 2 * qx + 5) * 8192];
            }
        }
    }
    // repack to adjacent-column pairs and store into [fh][ostr][2] cells
    #pragma unroll
    for (int a = 0; a < 2; ++a) {
        u32 o7[7];
        o7[0] = packh2(va[a][0], va[a][1]);
        o7[1] = packh2(va[a][2], va[a][3]);
        o7[2] = packh2(va[a][4], va[a][5]);
        o7[3] = packh2(va[a][6], vb[a][0]);
        o7[4] = packh2(vb[a][1], vb[a][2]);
        o7[5] = packh2(vb[a][3], vb[a][4]);
        o7[6] = packh2(vb[a][5], vb[a][6]);
        const int ch = 2 * cp + a;
        const int f0 = ch * 98 + oy2 * 7;    // parity = oy2&1 (uniform)
        const int fh0 = f0 >> 1;
        uint2* p2 = (uint2*)s2p;
        uint2 t;
        if ((oy2 & 1) == 0) {
            t.x = o7[0]; t.y = o7[1]; p2[(size_t)(fh0 + 0) * ostr + sl] = t;
            t.x = o7[2]; t.y = o7[3]; p2[(size_t)(fh0 + 1) * ostr + sl] = t;
            t.x = o7[4]; t.y = o7[5]; p2[(size_t)(fh0 + 2) * ostr + sl] = t;
            s2p[((size_t)(fh0 + 3) * ostr + sl) * 2] = o7[6];
        } else {
            s2p[((size_t)fh0 * ostr + sl) * 2 + 1] = o7[0];
            t.x = o7[1]; t.y = o7[2]; p2[(size_t)(fh0 + 1) * ostr + sl] = t;
            t.x = o7[3]; t.y = o7[4]; p2[(size_t)(fh0 + 2) * ostr + sl] = t;
            t.x = o7[5]; t.y = o7[6]; p2[(size_t)(fh0 + 3) * ostr + sl] = t;
        }
    }
}

// ---------------- C3 + S4 fused, grid (nb/256, 80) --------------------------
// blockIdx.y = oc*5 + y2. Window = 21 dwordx2 cells (42 adjacent-col pairs,
// rows 2y2..2y2+5). Odd outputs via shifted weight pairs (no alignbit).
template<int NIC>
__device__ __forceinline__ void c3_body(
    const uint2* __restrict__ s2c, const u32* __restrict__ wpk,
    const int* __restrict__ icl, int oc, int y2, int nb, int sl,
    float a2[2][10])
{
    #pragma unroll
    for (int e = 0; e < NIC; ++e) {          // fully unrolled plane loop
        const int ic = icl[e];
        const uint2* sp = s2c + (size_t)(ic * 49 + y2 * 7) * nb + sl;
        u32 wa_[6][7];                       // aligned pairs, rows 2y2..2y2+5
        #pragma unroll
        for (int k = 0; k < 21; ++k) {
            const uint2 v = sp[(size_t)k * nb];
            wa_[(2 * k) / 7][(2 * k) % 7]         = v.x;
            wa_[(2 * k + 1) / 7][(2 * k + 1) % 7] = v.y;
        }
        u32 wl[15], wls[15];                 // uniform f16 weight pairs
        #pragma unroll
        for (int i = 0; i < 15; ++i) wl[i]  = wpk[WPK_W3  + (oc * 6 + ic) * 15 + i];
        #pragma unroll
        for (int i = 0; i < 15; ++i) wls[i] = wpk[WPK_W3S + (oc * 6 + ic) * 15 + i];
        #pragma unroll
        for (int r = 0; r < 6; ++r) {
            const u32* wa = wa_[r];
            #pragma unroll
            for (int u = 0; u < 2; ++u) {
                const int ky = r - u;
                if (ky < 0 || ky > 4) continue;
                const u32 w0 = wl[ky * 3 + 0];
                const u32 w1 = wl[ky * 3 + 1];
                const u32 w2 = wl[ky * 3 + 2];
                const u32 v0 = wls[ky * 3 + 0];
                const u32 v1 = wls[ky * 3 + 1];
                const u32 v2 = wls[ky * 3 + 2];
                #pragma unroll
                for (int p = 0; p < 5; ++p) {
                    a2[u][2 * p]     = dot2(wa[p], w0, dot2(wa[p + 1], w1, dot2(wa[p + 2], w2, a2[u][2 * p])));
                    a2[u][2 * p + 1] = dot2(wa[p], v0, dot2(wa[p + 1], v1, dot2(wa[p + 2], v2, a2[u][2 * p + 1])));
                }
            }
        }
    }
}

__global__ __launch_bounds__(256) void k_c3s4(
    const u32* __restrict__ s2p, const u32* __restrict__ wpk,
    const float* __restrict__ b3, const float* __restrict__ s4w,
    const float* __restrict__ s4b, u32* __restrict__ s4p, int nb)
{
    const int sl = blockIdx.x * 256 + threadIdx.x;
    const int oc = blockIdx.y / 5;
    const int y2 = blockIdx.y % 5;
    const uint2* s2c = (const uint2*)s2p;
    const int* icl = &C3_ICL[oc * 6];
    const float bbv = b3[oc];

    float a2[2][10];
    #pragma unroll
    for (int u = 0; u < 2; ++u)
        #pragma unroll
        for (int ox = 0; ox < 10; ++ox) a2[u][ox] = bbv;

    switch (C3_NIC[oc]) {                    // uniform scalar branch
        case 3:  c3_body<3>(s2c, wpk, icl, oc, y2, nb, sl, a2); break;
        case 4:  c3_body<4>(s2c, wpk, icl, oc, y2, nb, sl, a2); break;
        default: c3_body<6>(s2c, wpk, icl, oc, y2, nb, sl, a2); break;
    }

    // tanh, then S4 reshape-flat pooling over local flat f = u*10+ox
    float tv[20];
    #pragma unroll
    for (int u = 0; u < 2; ++u)
        #pragma unroll
        for (int ox = 0; ox < 10; ++ox) tv[u * 10 + ox] = tact(a2[u][ox]);
    const float swv = s4w[oc], sbv = s4b[oc];
    float so[5];
    #pragma unroll
    for (int x2 = 0; x2 < 5; ++x2)
        so[x2] = tact(0.25f * (tv[x2 * 4] + tv[x2 * 4 + 1] + tv[x2 * 4 + 2] + tv[x2 * 4 + 3]) * swv + sbv);
    const size_t g = (size_t)(oc * 5 + y2) * 3;
    s4p[(g + 0) * nb + sl] = packh2(so[0], so[1]);
    s4p[(g + 1) * nb + sl] = packh2(so[2], so[3]);
    s4p[(g + 2) * nb + sl] = packh2(so[4], 0.0f);
}

// ---------------- C5: 120-ch GEMV over 240 s4 pairs, grid (nb/256, 12) ------
__global__ __launch_bounds__(256) void k_c5(
    const u32* __restrict__ s4p, const u32* __restrict__ wpk,
    const float* __restrict__ b5, u32* __restrict__ h5p, int nb)
{
    const int sl = blockIdx.x * 256 + threadIdx.x;
    const int chg = blockIdx.y;              // channels chg*10 .. chg*10+9
    const u32* wp = wpk + WPK_W5 + chg * 10 * 240;
    float acc[10];
    #pragma unroll
    for (int c = 0; c < 10; ++c) acc[c] = b5[chg * 10 + c];
    #pragma unroll 4
    for (int i = 0; i < 240; ++i) {
        const u32 v = s4p[(size_t)i * nb + sl];
        #pragma unroll
        for (int c = 0; c < 10; ++c)
            acc[c] = dot2(v, wp[c * 240 + i], acc[c]);   // uniform -> s_load
    }
    #pragma unroll
    for (int j = 0; j < 5; ++j)
        h5p[(size_t)(chg * 5 + j) * nb + sl] =
            packh2(tact(acc[2 * j]), tact(acc[2 * j + 1]));
}

// ---------------- F6: 84-out GEMV over 60 h5 pairs, grid (nb/256, 6) --------
__global__ __launch_bounds__(256) void k_f6(
    const u32* __restrict__ h5p, const u32* __restrict__ wpk,
    const float* __restrict__ f6b, u32* __restrict__ h6p, int nb)
{
    const int sl = blockIdx.x * 256 + threadIdx.x;
    const int og = blockIdx.y;               // outputs og*14 .. og*14+13
    const u32* wp = wpk + WPK_F6 + og * 14 * 60;
    float acc[14];
    #pragma unroll
    for (int o = 0; o < 14; ++o) acc[o] = f6b[og * 14 + o];
    #pragma unroll 4
    for (int i = 0; i < 60; ++i) {
        const u32 v = h5p[(size_t)i * nb + sl];
        #pragma unroll
        for (int o = 0; o < 14; ++o)
            acc[o] = dot2(v, wp[o * 60 + i], acc[o]);    // uniform -> s_load
    }
    #pragma unroll
    for (int j = 0; j < 7; ++j)
        h6p[(size_t)(og * 7 + j) * nb + sl] =
            packh2(tact(acc[2 * j]), tact(acc[2 * j + 1]));
}

// ---------------- RBF head, grid (nb/256, 5): 2 classes per block -----------
__global__ __launch_bounds__(256) void k_rbf(
    const u32* __restrict__ h6p, const float* __restrict__ rbf,
    float* __restrict__ out, int nb)
{
    const int sl = blockIdx.x * 256 + threadIdx.x;
    const int gy = blockIdx.y;
    float hv[84];
    #pragma unroll
    for (int i = 0; i < 42; ++i) {
        const u32 v = h6p[(size_t)i * nb + sl];
        hv[2 * i]     = f16lo(v);
        hv[2 * i + 1] = f16hi(v);
    }
    #pragma unroll
    for (int a = 0; a < 2; ++a) {
        const int c = 2 * gy + a;
        float acc = 0.0f;
        #pragma unroll 4
        for (int i = 0; i < 84; ++i) {
            float d = hv[i] - rbf[c * 84 + i];   // uniform -> s_load
            acc += d * d;
        }
        out[(size_t)sl * 10 + c] = acc;
    }
}

extern "C" void kernel_launch(void* const* d_in, const int* in_sizes, int n_in,
                              void* d_out, int out_size, void* d_ws, size_t ws_size,
                              hipStream_t stream)
{
    const float* x    = (const float*)d_in[0];
    const float* w1   = (const float*)d_in[1];
    const float* b1   = (const float*)d_in[2];
    const float* s2w  = (const float*)d_in[3];
    const float* s2b  = (const float*)d_in[4];
    const float* w3   = (const float*)d_in[5];
    const float* b3   = (const float*)d_in[6];
    const float* s4w  = (const float*)d_in[7];
    const float* s4b  = (const float*)d_in[8];
    const float* w5   = (const float*)d_in[9];
    const float* b5   = (const float*)d_in[10];
    const float* f6w  = (const float*)d_in[11];
    const float* f6b  = (const float*)d_in[12];
    const float* rbfw = (const float*)d_in[13];
    float* out = (float*)d_out;
    char* ws = (char*)d_ws;

    // Weight pack at the tail of d_out (dead until k_rbf; k_rbf never reads
    // it and rewrites every byte of out at the end of each plan/chunk order).
    u32* WPK = (u32*)((char*)d_out +
                      (((size_t)out_size - (size_t)(WPK_N * 4)) & ~(size_t)7));
    k_wpack<<<dim3((WPK_N + 255) / 256), 256, 0, stream>>>(w1, w3, w5, f6w, WPK);

    if (ws_size >= 55312384) {
        // ---- Plan A: full-batch tail (10 dispatches) ----
        u32* S2P = (u32*)(ws);                       // 38,535,168 B (cells)
        u32* XP  = (u32*)(ws + 38535168);            // 16,777,216 B (front)
        u32* S4P = (u32*)(ws + 38535168);            // 15,728,640 B (after front)
        u32* H5P = (u32*)(ws);                       //  3,932,160 B (after c3s4)
        u32* H6P = (u32*)(ws + 4194304);             //  2,752,512 B
        for (int c = 0; c < 2; ++c) {
            k_tr  <<<dim3(128, 16), 256, 0, stream>>>(x + (size_t)c * 8192 * 1024, XP);
            k_c1s2<<<dim3(32, 42), 256, 0, stream>>>(XP, WPK, b1, s2w, s2b,
                                                     S2P + (size_t)c * 16384, 16384);
        }
        k_c3s4<<<dim3(64, 80), 256, 0, stream>>>(S2P, WPK, b3, s4w, s4b, S4P, 16384);
        k_c5  <<<dim3(64, 12), 256, 0, stream>>>(S4P, WPK, b5, H5P, 16384);
        k_f6  <<<dim3(64, 6), 256, 0, stream>>>(H5P, WPK, f6b, H6P, 16384);
        k_rbf <<<dim3(64, 5), 256, 0, stream>>>(H6P, rbfw, out, 16384);
    } else {
        // ---- Plan B: 2 chunks (13 dispatches) ----
        u32* XP  = (u32*)(ws);                       // 16,777,216 B
        u32* S2P = (u32*)(ws + 16777216);            // 19,267,584 B
        u32* S4P = (u32*)(ws);                       //  7,864,320 B (XP dead)
        u32* H5P = (u32*)(ws + 7864320);             //  1,966,080 B
        u32* H6P = (u32*)(ws + 9830400);             //  1,376,256 B
        for (int c = 0; c < 2; ++c) {
            k_tr  <<<dim3(128, 16), 256, 0, stream>>>(x + (size_t)c * 8192 * 1024, XP);
            k_c1s2<<<dim3(32, 42), 256, 0, stream>>>(XP, WPK, b1, s2w, s2b, S2P, 8192);
            k_c3s4<<<dim3(32, 80), 256, 0, stream>>>(S2P, WPK, b3, s4w, s4b, S4P, 8192);
            k_c5  <<<dim3(32, 12), 256, 0, stream>>>(S4P, WPK, b5, H5P, 8192);
            k_f6  <<<dim3(32, 6), 256, 0, stream>>>(H5P, WPK, f6b, H6P, 8192);
            k_rbf <<<dim3(32, 5), 256, 0, stream>>>(H6P, rbfw, out + (size_t)c * 8192 * 10, 8192);
        }
    }
}